// Round 3
// baseline (554.401 us; speedup 1.0000x reference)
//
#include <hip/hip_runtime.h>
#include <math.h>

typedef __attribute__((ext_vector_type(8))) _Float16 fp16x8;
typedef __attribute__((ext_vector_type(4))) _Float16 fp16x4;
typedef __attribute__((ext_vector_type(4))) float floatx4;

#define HID 512
#define TRIC 78
#define OUTC 79
#define BATCH 262144
#define HPAD 528   // halfs per h row (512 + 16 pad): row stride 1056 B, mod 128 = 32
#define OPAD 84    // floats per out-tile row

// ws layout in halfs (UNCHANGED from r1/r2 — A/B frag lane maps are symmetric,
// so the same frags serve as A-operands of the transposed GEMMs):
#define W2P_OFF 16384
#define W3P_OFF 278528
#define X_OFF 33792   // halfs: x stage [64][16] fp16 after the h region

__global__ __launch_bounds__(256) void prep_kernel(const float* __restrict__ W1,
                                                   const float* __restrict__ W2,
                                                   const float* __restrict__ W3,
                                                   _Float16* __restrict__ wsh) {
  int g = blockIdx.x * 256 + threadIdx.x;
  int lane = g & 63;
  int l15 = lane & 15, q = lane >> 4;
  fp16x8 v;
  if (g < 2048) {
    // W1ᵀ A-frag: lane holds W1[k][c], c = ct*16 + l15, k = q*8+j (pad K 12->32)
    int ct = g >> 6;
    int c = ct * 16 + l15;
#pragma unroll
    for (int j = 0; j < 8; ++j) {
      int k = q * 8 + j;
      v[j] = (k < 12) ? (_Float16)W1[k * HID + c] : (_Float16)0.f;
    }
    *(fp16x8*)(wsh + (size_t)g * 8) = v;
  } else if (g < 34816) {
    // W2ᵀ A-frag: W2[k][c]
    int h = g - 2048;
    int fk = h >> 6;                 // fk = ct*16 + kb
    int kb = fk & 15, ct = fk >> 4;
    int c = ct * 16 + l15;
    int kbase = kb * 32 + q * 8;
#pragma unroll
    for (int j = 0; j < 8; ++j) v[j] = (_Float16)W2[(kbase + j) * HID + c];
    *(fp16x8*)(wsh + W2P_OFF + (size_t)h * 8) = v;
  } else if (g < 39936) {
    // W3ᵀ A-frag: W3[k][c], pad c 79->80
    int h = g - 34816;
    int fk = h >> 6;
    int kb = fk & 15, ct = fk >> 4;
    int c = ct * 16 + l15;
    int kbase = kb * 32 + q * 8;
#pragma unroll
    for (int j = 0; j < 8; ++j)
      v[j] = (c < OUTC) ? (_Float16)W3[(kbase + j) * OUTC + c] : (_Float16)0.f;
    *(fp16x8*)(wsh + W3P_OFF + (size_t)h * 8) = v;
  }
}

__device__ __forceinline__ float softplus_f(float v) {
  return fmaxf(v, 0.f) + log1pf(expf(-fabsf(v)));
}

__global__ __launch_bounds__(256, 2) void fused_kernel(const float* __restrict__ x,
                                                       const float* __restrict__ b1,
                                                       const float* __restrict__ b2,
                                                       const float* __restrict__ b3,
                                                       const _Float16* __restrict__ wsh,
                                                       float* __restrict__ out) {
  __shared__ __align__(16) _Float16 hbuf[X_OFF + 1024];  // 68 KB: h[64][528] + x[64][16]
  const int tid = threadIdx.x;
  const int wave = tid >> 6, lane = tid & 63;
  const int l15 = lane & 15, quad = lane >> 4;
  const int r0 = blockIdx.x * 64;

  // ---- stage x tile -> fp16 [64][16] (k 12..15 zero) ----
  {
    _Float16* xs = hbuf + X_OFF;
    const float* xg = x + (size_t)r0 * 12;
#pragma unroll
    for (int s = 0; s < 3; ++s) {
      int e = tid + s * 256;
      int row = e / 12, col = e - row * 12;
      xs[row * 16 + col] = (_Float16)xg[e];
    }
    xs[(tid >> 2) * 16 + 12 + (tid & 3)] = (_Float16)0.f;
  }
  __syncthreads();

  const fp16x8* w1p = (const fp16x8*)wsh;
  const fp16x8* w2p = (const fp16x8*)(wsh + W2P_OFF);
  const fp16x8* w3p = (const fp16x8*)(wsh + W3P_OFF);

  fp16x8 zf;
#pragma unroll
  for (int j = 0; j < 8; ++j) zf[j] = (_Float16)0.f;

  const floatx4 zero4 = {0.f, 0.f, 0.f, 0.f};
  floatx4 acc[8][4];  // [c-tile][batch-tile]; D: batch-row = l15, c = quad*4+r
#pragma unroll
  for (int ct = 0; ct < 8; ++ct)
#pragma unroll
    for (int nt = 0; nt < 4; ++nt) acc[ct][nt] = zero4;

  // ---- layer1: h1ᵀ = W1ᵀ xᵀ. Wave owns 128 h-cols (ct 0..7), all 64 rows ----
  {
    const _Float16* xs = hbuf + X_OFF;
    fp16x8 xb[4];
#pragma unroll
    for (int nt = 0; nt < 4; ++nt)
      xb[nt] = (quad < 2) ? *(const fp16x8*)(xs + (nt * 16 + l15) * 16 + quad * 8) : zf;
    fp16x8 a1[8];
#pragma unroll
    for (int ct = 0; ct < 8; ++ct) a1[ct] = w1p[(wave * 8 + ct) * 64 + lane];
#pragma unroll
    for (int ct = 0; ct < 8; ++ct)
#pragma unroll
      for (int nt = 0; nt < 4; ++nt)
        acc[ct][nt] = __builtin_amdgcn_mfma_f32_16x16x32_f16(a1[ct], xb[nt], acc[ct][nt], 0, 0, 0);
  }
  floatx4 bq[8];
#pragma unroll
  for (int ct = 0; ct < 8; ++ct)
    bq[ct] = *(const floatx4*)(b1 + wave * 128 + ct * 16 + quad * 4);

  // ---- epilogue1: relu+bias -> row-major h fp16, packed b64 writes ----
  // (x region disjoint from h region: no barrier needed before these writes)
#pragma unroll
  for (int ct = 0; ct < 8; ++ct)
#pragma unroll
    for (int nt = 0; nt < 4; ++nt) {
      fp16x4 p;
#pragma unroll
      for (int r = 0; r < 4; ++r) p[r] = (_Float16)fmaxf(acc[ct][nt][r] + bq[ct][r], 0.f);
      *(fp16x4*)(hbuf + (nt * 16 + l15) * HPAD + wave * 128 + ct * 16 + quad * 4) = p;
    }
  __syncthreads();

  // ---- layer2: h2ᵀ = W2ᵀ h1ᵀ, software-pipelined, no barrier in K-loop ----
#pragma unroll
  for (int ct = 0; ct < 8; ++ct)
#pragma unroll
    for (int nt = 0; nt < 4; ++nt) acc[ct][nt] = zero4;

  auto loadL2 = [&](int kb, fp16x8* a, fp16x8* b) {
#pragma unroll
    for (int ct = 0; ct < 8; ++ct) a[ct] = w2p[((wave * 8 + ct) * 16 + kb) * 64 + lane];
#pragma unroll
    for (int nt = 0; nt < 4; ++nt)
      b[nt] = *(const fp16x8*)(hbuf + (nt * 16 + l15) * HPAD + kb * 32 + quad * 8);
  };
  auto mfmaL2 = [&](const fp16x8* a, const fp16x8* b) {
#pragma unroll
    for (int ct = 0; ct < 8; ++ct)
#pragma unroll
      for (int nt = 0; nt < 4; ++nt)
        acc[ct][nt] = __builtin_amdgcn_mfma_f32_16x16x32_f16(a[ct], b[nt], acc[ct][nt], 0, 0, 0);
  };

  {
    fp16x8 aP[8], bP[4], aQ[8], bQ[4];
    loadL2(0, aP, bP);
#pragma unroll
    for (int kb = 0; kb < 16; kb += 2) {
      loadL2(kb + 1, aQ, bQ);
      mfmaL2(aP, bP);
      if (kb + 2 < 16) loadL2(kb + 2, aP, bP);
      mfmaL2(aQ, bQ);
    }
  }
#pragma unroll
  for (int ct = 0; ct < 8; ++ct)
    bq[ct] = *(const floatx4*)(b2 + wave * 128 + ct * 16 + quad * 4);

  __syncthreads();  // all waves done reading h1

  // ---- epilogue2: relu+bias -> h2 row-major (in place) ----
#pragma unroll
  for (int ct = 0; ct < 8; ++ct)
#pragma unroll
    for (int nt = 0; nt < 4; ++nt) {
      fp16x4 p;
#pragma unroll
      for (int r = 0; r < 4; ++r) p[r] = (_Float16)fmaxf(acc[ct][nt][r] + bq[ct][r], 0.f);
      *(fp16x4*)(hbuf + (nt * 16 + l15) * HPAD + wave * 128 + ct * 16 + quad * 4) = p;
    }
  __syncthreads();

  // ---- layer3: outᵀ = W3ᵀ h2ᵀ. Wave owns batch-tile = wave, 5 c-tiles ----
  floatx4 acc3[5];
#pragma unroll
  for (int mt = 0; mt < 5; ++mt) acc3[mt] = zero4;

  auto loadL3 = [&](int kb, fp16x8* a, fp16x8& b) {
#pragma unroll
    for (int mt = 0; mt < 5; ++mt) a[mt] = w3p[(mt * 16 + kb) * 64 + lane];
    b = *(const fp16x8*)(hbuf + (wave * 16 + l15) * HPAD + kb * 32 + quad * 8);
  };
  auto mfmaL3 = [&](const fp16x8* a, const fp16x8 b) {
#pragma unroll
    for (int mt = 0; mt < 5; ++mt)
      acc3[mt] = __builtin_amdgcn_mfma_f32_16x16x32_f16(a[mt], b, acc3[mt], 0, 0, 0);
  };
  {
    fp16x8 aP[5], aQ[5], bP, bQ;
    loadL3(0, aP, bP);
#pragma unroll
    for (int kb = 0; kb < 16; kb += 2) {
      loadL3(kb + 1, aQ, bQ);
      mfmaL3(aP, bP);
      if (kb + 2 < 16) loadL3(kb + 2, aP, bP);
      mfmaL3(aQ, bQ);
    }
  }
  floatx4 b3q[5];
#pragma unroll
  for (int mt = 0; mt < 4; ++mt) b3q[mt] = *(const floatx4*)(b3 + mt * 16 + quad * 4);
#pragma unroll
  for (int r = 0; r < 4; ++r) {
    int c = 64 + quad * 4 + r;
    b3q[4][r] = (c < OUTC) ? b3[c] : 0.f;
  }
  __syncthreads();  // all waves done reading h2 (out tile overlays h region)

  // ---- epilogue3: softplus -> fp32 out tile [64][84], b128 writes ----
  float* outf = (float*)hbuf;
#pragma unroll
  for (int mt = 0; mt < 5; ++mt) {
    floatx4 v;
#pragma unroll
    for (int r = 0; r < 4; ++r) v[r] = softplus_f(acc3[mt][r] + b3q[mt][r]);
    *(floatx4*)(outf + (wave * 16 + l15) * OPAD + mt * 16 + quad * 4) = v;
  }
  __syncthreads();

  // ---- MMT = L L^T, register-resident (r2 structure), stride 84 ----
  const float* of = (const float*)hbuf;
  const int rowl = tid >> 2;   // 0..63
  const int sub = tid & 3;
  const float* Lr = of + rowl * OPAD;

  float Lj[3][12];
#pragma unroll
  for (int t = 0; t < 3; ++t) {
    int j = sub + 4 * t;
    int tj = (j * (j + 1)) >> 1;
#pragma unroll
    for (int k = 0; k < 12; ++k) {
      float v = Lr[tj + k];
      Lj[t][k] = (k <= j) ? v : 0.f;
    }
  }

  float* mmt = out + (size_t)(r0 + rowl) * 144;
#pragma unroll
  for (int i = 0; i < 12; ++i) {
    int ti = (i * (i + 1)) >> 1;
    float Li[12];
#pragma unroll
    for (int k = 0; k <= i; ++k) Li[k] = Lr[ti + k];
#pragma unroll
    for (int t = 0; t < 3; ++t) {
      float s = 0.f;
#pragma unroll
      for (int k = 0; k <= i; ++k) s = fmaf(Li[k], Lj[t][k], s);
      __builtin_nontemporal_store(s, mmt + i * 12 + sub + 4 * t);
    }
  }
  if (sub == 0) {
    __builtin_nontemporal_store(Lr[TRIC], out + (size_t)BATCH * 144 + r0 + rowl);
  }
}

extern "C" void kernel_launch(void* const* d_in, const int* in_sizes, int n_in,
                              void* d_out, int out_size, void* d_ws, size_t ws_size,
                              hipStream_t stream) {
  const float* x  = (const float*)d_in[0];
  const float* W1 = (const float*)d_in[1];
  const float* b1 = (const float*)d_in[2];
  const float* W2 = (const float*)d_in[3];
  const float* b2 = (const float*)d_in[4];
  const float* W3 = (const float*)d_in[5];
  const float* b3 = (const float*)d_in[6];
  float* out = (float*)d_out;
  _Float16* wsh = (_Float16*)d_ws;

  prep_kernel<<<156, 256, 0, stream>>>(W1, W2, W3, wsh);
  fused_kernel<<<BATCH / 64, 256, 0, stream>>>(x, b1, b2, b3, wsh, out);
}

// Round 4
// 386.080 us; speedup vs baseline: 1.4360x; 1.4360x over previous
//
#include <hip/hip_runtime.h>
#include <math.h>

typedef __attribute__((ext_vector_type(8))) _Float16 fp16x8;
typedef __attribute__((ext_vector_type(4))) _Float16 fp16x4;
typedef __attribute__((ext_vector_type(4))) float floatx4;

#define HID 512
#define TRIC 78
#define OUTC 79
#define BATCH 262144
#define HPAD 520          // halfs/row: stride 1040 B = 260 dwords ≡ 4 (mod 32) -> uniform banks
#define OPAD 84           // floats/row of L tile
#define MPAD 148          // floats/row of M tile (148*4 B: 8 consecutive rows hit 8 distinct bank-quads)
#define ML_OFF 6144       // float offset of M tile region (24576 B)
#define XPAD 24           // halfs/row of x stage
#define X_OFF 33280       // half offset of x region (= 64*520)

// ws layout in halfs (A-frags of the transposed GEMMs; lane map A[c=l&15][k=q*8+j]):
#define W2P_OFF 16384
#define W3P_OFF 278528

__global__ __launch_bounds__(256) void prep_kernel(const float* __restrict__ W1,
                                                   const float* __restrict__ W2,
                                                   const float* __restrict__ W3,
                                                   _Float16* __restrict__ wsh) {
  int g = blockIdx.x * 256 + threadIdx.x;
  int lane = g & 63;
  int l15 = lane & 15, q = lane >> 4;
  fp16x8 v;
  if (g < 2048) {
    int ct = g >> 6;
    int c = ct * 16 + l15;
#pragma unroll
    for (int j = 0; j < 8; ++j) {
      int k = q * 8 + j;
      v[j] = (k < 12) ? (_Float16)W1[k * HID + c] : (_Float16)0.f;
    }
    *(fp16x8*)(wsh + (size_t)g * 8) = v;
  } else if (g < 34816) {
    int h = g - 2048;
    int fk = h >> 6;                 // fk = ct*16 + kb
    int kb = fk & 15, ct = fk >> 4;
    int c = ct * 16 + l15;
    int kbase = kb * 32 + q * 8;
#pragma unroll
    for (int j = 0; j < 8; ++j) v[j] = (_Float16)W2[(kbase + j) * HID + c];
    *(fp16x8*)(wsh + W2P_OFF + (size_t)h * 8) = v;
  } else if (g < 39936) {
    int h = g - 34816;
    int fk = h >> 6;
    int kb = fk & 15, ct = fk >> 4;
    int c = ct * 16 + l15;
    int kbase = kb * 32 + q * 8;
#pragma unroll
    for (int j = 0; j < 8; ++j)
      v[j] = (c < OUTC) ? (_Float16)W3[(kbase + j) * OUTC + c] : (_Float16)0.f;
    *(fp16x8*)(wsh + W3P_OFF + (size_t)h * 8) = v;
  }
}

__device__ __forceinline__ float softplus_f(float v) {
  return fmaxf(v, 0.f) + log1pf(expf(-fabsf(v)));
}

__global__ __launch_bounds__(512, 4) void fused_kernel(const float* __restrict__ x,
                                                       const float* __restrict__ b1,
                                                       const float* __restrict__ b2,
                                                       const float* __restrict__ b3,
                                                       const _Float16* __restrict__ wsh,
                                                       float* __restrict__ out) {
  __shared__ __align__(16) _Float16 hbuf[X_OFF + 64 * XPAD];  // 68 KB
  const int tid = threadIdx.x;
  const int wave = tid >> 6, lane = tid & 63;
  const int l15 = lane & 15, quad = lane >> 4;
  const int r0 = blockIdx.x * 64;

  // ---- stage x tile -> fp16 [64][XPAD] (cols 12..15 zeroed; 16..23 never read) ----
  {
    _Float16* xs = hbuf + X_OFF;
    const float* xg = x + (size_t)r0 * 12;
    if (tid < 256) {
      int e = 512 + tid;
      int row = e / 12, col = e - row * 12;
      xs[row * XPAD + col] = (_Float16)xg[e];
      xs[(tid >> 2) * XPAD + 12 + (tid & 3)] = (_Float16)0.f;
    }
    {
      int row = tid / 12, col = tid - row * 12;
      xs[row * XPAD + col] = (_Float16)xg[tid];
    }
  }
  __syncthreads();

  const fp16x8* w1p = (const fp16x8*)wsh;
  const fp16x8* w2p = (const fp16x8*)(wsh + W2P_OFF);
  const fp16x8* w3p = (const fp16x8*)(wsh + W3P_OFF);

  fp16x8 zf;
#pragma unroll
  for (int j = 0; j < 8; ++j) zf[j] = (_Float16)0.f;

  const floatx4 zero4 = {0.f, 0.f, 0.f, 0.f};
  floatx4 acc[4][4];  // [c-tile][batch-tile]; D: batch-row = l15, c = quad*4+r
#pragma unroll
  for (int ct = 0; ct < 4; ++ct)
#pragma unroll
    for (int nt = 0; nt < 4; ++nt) acc[ct][nt] = zero4;

  // ---- layer1: h1ᵀ = W1ᵀ xᵀ. Wave owns 64 h-cols (ct 0..3), all 64 rows ----
  {
    const _Float16* xs = hbuf + X_OFF;
    fp16x8 xb[4];
#pragma unroll
    for (int nt = 0; nt < 4; ++nt)
      xb[nt] = (quad < 2) ? *(const fp16x8*)(xs + (nt * 16 + l15) * XPAD + quad * 8) : zf;
#pragma unroll
    for (int ct = 0; ct < 4; ++ct) {
      fp16x8 a1 = w1p[(wave * 4 + ct) * 64 + lane];
#pragma unroll
      for (int nt = 0; nt < 4; ++nt)
        acc[ct][nt] = __builtin_amdgcn_mfma_f32_16x16x32_f16(a1, xb[nt], acc[ct][nt], 0, 0, 0);
    }
  }
  floatx4 bq[4];
#pragma unroll
  for (int ct = 0; ct < 4; ++ct)
    bq[ct] = *(const floatx4*)(b1 + wave * 64 + ct * 16 + quad * 4);

  // ---- epilogue1: relu+bias -> row-major h fp16 (x region disjoint) ----
#pragma unroll
  for (int ct = 0; ct < 4; ++ct)
#pragma unroll
    for (int nt = 0; nt < 4; ++nt) {
      fp16x4 p;
#pragma unroll
      for (int r = 0; r < 4; ++r) p[r] = (_Float16)fmaxf(acc[ct][nt][r] + bq[ct][r], 0.f);
      *(fp16x4*)(hbuf + (nt * 16 + l15) * HPAD + wave * 64 + ct * 16 + quad * 4) = p;
    }
  __syncthreads();

  // ---- layer2: h2ᵀ = W2ᵀ h1ᵀ; no barrier inside K-loop ----
#pragma unroll
  for (int ct = 0; ct < 4; ++ct)
#pragma unroll
    for (int nt = 0; nt < 4; ++nt) acc[ct][nt] = zero4;

#pragma unroll 2
  for (int kb = 0; kb < 16; ++kb) {
    fp16x8 a[4], b[4];
#pragma unroll
    for (int ct = 0; ct < 4; ++ct) a[ct] = w2p[((wave * 4 + ct) * 16 + kb) * 64 + lane];
#pragma unroll
    for (int nt = 0; nt < 4; ++nt)
      b[nt] = *(const fp16x8*)(hbuf + (nt * 16 + l15) * HPAD + kb * 32 + quad * 8);
#pragma unroll
    for (int ct = 0; ct < 4; ++ct)
#pragma unroll
      for (int nt = 0; nt < 4; ++nt)
        acc[ct][nt] = __builtin_amdgcn_mfma_f32_16x16x32_f16(a[ct], b[nt], acc[ct][nt], 0, 0, 0);
  }
#pragma unroll
  for (int ct = 0; ct < 4; ++ct)
    bq[ct] = *(const floatx4*)(b2 + wave * 64 + ct * 16 + quad * 4);

  __syncthreads();  // all waves done reading h1

  // ---- epilogue2: relu+bias -> h2 row-major (in place) ----
#pragma unroll
  for (int ct = 0; ct < 4; ++ct)
#pragma unroll
    for (int nt = 0; nt < 4; ++nt) {
      fp16x4 p;
#pragma unroll
      for (int r = 0; r < 4; ++r) p[r] = (_Float16)fmaxf(acc[ct][nt][r] + bq[ct][r], 0.f);
      *(fp16x4*)(hbuf + (nt * 16 + l15) * HPAD + wave * 64 + ct * 16 + quad * 4) = p;
    }
  __syncthreads();

  // ---- layer3: outᵀ = W3ᵀ h2ᵀ. wave -> m-tile = wave>>1; even wave: c-tiles {0,1,2},
  //      odd wave: {3,4} ----
  const int mt3 = wave >> 1;
  const int codd = wave & 1;
  const int c0 = codd ? 3 : 0;
  const int nct = codd ? 2 : 3;
  floatx4 acc3[3];
#pragma unroll
  for (int j = 0; j < 3; ++j) acc3[j] = zero4;

#pragma unroll 2
  for (int kb = 0; kb < 16; ++kb) {
    fp16x8 bfrag = *(const fp16x8*)(hbuf + (mt3 * 16 + l15) * HPAD + kb * 32 + quad * 8);
#pragma unroll
    for (int j = 0; j < 3; ++j)
      if (j < nct)
        acc3[j] = __builtin_amdgcn_mfma_f32_16x16x32_f16(
            w3p[((c0 + j) * 16 + kb) * 64 + lane], bfrag, acc3[j], 0, 0, 0);
  }
  floatx4 b3q[3];
#pragma unroll
  for (int j = 0; j < 3; ++j)
    if (j < nct) {
#pragma unroll
      for (int r = 0; r < 4; ++r) {
        int c = (c0 + j) * 16 + quad * 4 + r;
        b3q[j][r] = (c < OUTC) ? b3[c] : 0.f;
      }
    }
  __syncthreads();  // all waves done reading h2

  // ---- epilogue3: softplus -> L tile [64][OPAD] fp32 at LDS base ----
  float* outf = (float*)hbuf;
#pragma unroll
  for (int j = 0; j < 3; ++j)
    if (j < nct) {
      floatx4 v;
#pragma unroll
      for (int r = 0; r < 4; ++r) v[r] = softplus_f(acc3[j][r] + b3q[j][r]);
      *(floatx4*)(outf + (mt3 * 16 + l15) * OPAD + (c0 + j) * 16 + quad * 4) = v;
    }
  __syncthreads();

  // ---- MMT register-resident: 8 threads/row; thread owns cols {sub, sub+8(sub<4)} ----
  {
    const float* Lbase = (const float*)hbuf;
    float* Mbase = (float*)hbuf + ML_OFF;   // disjoint from L region: no barrier needed
    const int rowl = tid >> 3;
    const int sub = tid & 7;
    const float* Lr = Lbase + rowl * OPAD;

    float Lj[2][12];
#pragma unroll
    for (int k = 0; k < 12; ++k) {
      float v0 = Lr[((sub * (sub + 1)) >> 1) + k];
      Lj[0][k] = (k <= sub) ? v0 : 0.f;
    }
    const int j1 = sub + 8;
    if (sub < 4) {
#pragma unroll
      for (int k = 0; k < 12; ++k) {
        float v1 = Lr[((j1 * (j1 + 1)) >> 1) + k];
        Lj[1][k] = (k <= j1) ? v1 : 0.f;
      }
    }

    float* Mr = Mbase + rowl * MPAD;
#pragma unroll
    for (int i = 0; i < 12; ++i) {
      int ti = (i * (i + 1)) >> 1;
      float Li[12];
#pragma unroll
      for (int k = 0; k <= i; ++k) Li[k] = Lr[ti + k];
      float s0 = 0.f;
#pragma unroll
      for (int k = 0; k <= i; ++k) s0 = fmaf(Li[k], Lj[0][k], s0);
      Mr[i * 12 + sub] = s0;
      if (sub < 4) {
        float s1 = 0.f;
#pragma unroll
        for (int k = 0; k <= i; ++k) s1 = fmaf(Li[k], Lj[1][k], s1);
        Mr[i * 12 + j1] = s1;
      }
    }
  }
  __syncthreads();

  // ---- coalesced copy-out: M [64][144] via float4, plus c column ----
  {
    const float* Mbase = (const float*)hbuf + ML_OFF;
    float* og = out + (size_t)r0 * 144;
#pragma unroll
    for (int s = 0; s < 4; ++s) {
      int e4 = tid + s * 512;            // 0..2047
      int row = e4 / 36, c4 = e4 - row * 36;
      *(floatx4*)(og + row * 144 + c4 * 4) = *(const floatx4*)(Mbase + row * MPAD + c4 * 4);
    }
    if (tid < 256) {
      int e4 = 2048 + tid;
      int row = e4 / 36, c4 = e4 - row * 36;
      *(floatx4*)(og + row * 144 + c4 * 4) = *(const floatx4*)(Mbase + row * MPAD + c4 * 4);
    }
    if (tid < 64) {
      const float* Lbase = (const float*)hbuf;
      out[(size_t)BATCH * 144 + r0 + tid] = Lbase[tid * OPAD + TRIC];
    }
  }
}

extern "C" void kernel_launch(void* const* d_in, const int* in_sizes, int n_in,
                              void* d_out, int out_size, void* d_ws, size_t ws_size,
                              hipStream_t stream) {
  const float* x  = (const float*)d_in[0];
  const float* W1 = (const float*)d_in[1];
  const float* b1 = (const float*)d_in[2];
  const float* W2 = (const float*)d_in[3];
  const float* b2 = (const float*)d_in[4];
  const float* W3 = (const float*)d_in[5];
  const float* b3 = (const float*)d_in[6];
  float* out = (float*)d_out;
  _Float16* wsh = (_Float16*)d_ws;

  prep_kernel<<<156, 256, 0, stream>>>(W1, W2, W3, wsh);
  fused_kernel<<<BATCH / 64, 512, 0, stream>>>(x, b1, b2, b3, wsh, out);
}